// Round 4
// baseline (408.383 us; speedup 1.0000x reference)
//
#include <hip/hip_runtime.h>

// LatentClassifier collapse (all f32 I/O):
//   All depth-loop layernorms act on singleton axes -> LN(x) == bias exactly.
//   => h = x + c[t];  out = (gelu((x+c) @ P^T + pooler_b)) @ cls_w^T + cls_b
//   c per-column => (x+c)@P^T = x@P^T + d[s], d[s] = sum_t c[t]*P[s,t]
// FP32 inputs, no fp32 MFMA -> convert x,P to bf16 once (ws), one 4096^3 bf16
// MFMA GEMM with fused gelu/cls epilogue atomicAdd into d_out.
//
// R4: 256x128 + per-K syncthreads: 135us, MfmaUtil 44%.
// R6: 8-phase, NO frag reuse (48 ds_read/wave/Ktile): 177us, 31.5%.
// R7: frag reuse (32 reads/Ktile) + vmcnt(6) ring: 154us, 37% -- but my
//     hand fences (lgkmcnt(0)+sched_barrier(0) x8/body) forced full-drain
//     before every MFMA cluster = m141 order-pinning failure mode.
// R8: R7 minus ALL scheduling fences. Compiler emits fine-grained lgkmcnt
//     so MFMAs issue as their own frags land (read||MFMA overlap within and
//     across waves). Barriers + vmcnt ring unchanged (correctness skeleton).

#define K_DIM 4096

typedef __bf16 bf16x8 __attribute__((ext_vector_type(8)));
typedef float f32x4 __attribute__((ext_vector_type(4)));

__device__ __forceinline__ ushort f2bf(float f) {
    unsigned int u = __float_as_uint(f);
    u = (u + 0x7fffu + ((u >> 16) & 1u)) >> 16;  // RTNE
    return (ushort)u;
}

__device__ __forceinline__ float gelu_exact(float x) {
    return 0.5f * x * (1.0f + erff(x * 0.70710678118654752440f));
}

__device__ __forceinline__ void gld16(const void* g, void* l) {
    __builtin_amdgcn_global_load_lds(
        (__attribute__((address_space(1))) void*)(g),
        (__attribute__((address_space(3))) void*)(l), 16, 0, 0);
}

// ---------- K1: c[t] (+R rowsum inline, beta==0 fast path); init e, out -------
__global__ __launch_bounds__(256) void c_kernel(const float* __restrict__ ln1_b,
                                                const float* __restrict__ cp1_w,
                                                const float* __restrict__ cp1_b,
                                                const float* __restrict__ sgu_ln_b,
                                                const float* __restrict__ sgu_proj_w,
                                                const float* __restrict__ sgu_proj_b,
                                                const float* __restrict__ cp2_w,
                                                const float* __restrict__ cp2_b,
                                                const float* __restrict__ cls_b,
                                                const float* __restrict__ pooler_b,
                                                float* __restrict__ c,
                                                float* __restrict__ e,
                                                float* __restrict__ out) {
    int t = blockIdx.x * 256 + threadIdx.x;  // 0..4095
    float cv = 0.0f;
#pragma unroll
    for (int i = 0; i < 2; ++i) {
        float alpha = gelu_exact(ln1_b[i] * cp1_w[i * 2 + 0] + cp1_b[i * 2 + 0]);
        float beta  = sgu_ln_b[i];
        float Ri = 0.0f;
        if (beta != 0.0f) {  // never taken with these inputs; kept for correctness
            const float* pr = sgu_proj_w + ((size_t)i * 4096 + t) * K_DIM;
            for (int k = 0; k < K_DIM; k += 4) {
                float4 pv = *(const float4*)&pr[k];
                Ri += pv.x + pv.y + pv.z + pv.w;
            }
        }
        float v = beta * Ri + sgu_proj_b[i * 4096 + t];
        cv += alpha * v * cp2_w[i] + cp2_b[i];
    }
    c[t]   = cv;
    e[t]   = pooler_b[t];  // e accumulated by cvt2_kernel atomics
    out[t] = cls_b[0];     // d_out poisoned before every call -> re-init here
}

// ---------- K2: f32->bf16 convert of x and pooler_w; P-half also accumulates
//               e[row] += sum_col P[row,col]*c[col] (wave-reduced atomic) ------
__global__ __launch_bounds__(256) void cvt2_kernel(const float* __restrict__ s0,
                                                   ushort* __restrict__ d0,
                                                   const float* __restrict__ s1,
                                                   ushort* __restrict__ d1,
                                                   const float* __restrict__ c,
                                                   float* __restrict__ e) {
    int b = blockIdx.x;
    bool isP = (b >= 8192);
    const float* src = isP ? s1 : s0;
    ushort* dst = isP ? d1 : d0;
    int i = (b & 8191) * 256 + threadIdx.x;  // 8 floats each
    const float4* s4 = (const float4*)src + (size_t)i * 2;
    float4 a = s4[0], q = s4[1];
    union { ushort u[8]; uint4 v; } r;
    r.u[0] = f2bf(a.x); r.u[1] = f2bf(a.y); r.u[2] = f2bf(a.z); r.u[3] = f2bf(a.w);
    r.u[4] = f2bf(q.x); r.u[5] = f2bf(q.y); r.u[6] = f2bf(q.z); r.u[7] = f2bf(q.w);
    ((uint4*)dst)[i] = r.v;
    if (isP) {
        // wave's 64 units are 512 consecutive floats inside row i>>9
        int col = (i << 3) & 4095;
        float s = a.x * c[col + 0] + a.y * c[col + 1] + a.z * c[col + 2] + a.w * c[col + 3]
                + q.x * c[col + 4] + q.y * c[col + 5] + q.z * c[col + 6] + q.w * c[col + 7];
#pragma unroll
        for (int m = 1; m < 64; m <<= 1) s += __shfl_xor(s, m);
        if ((threadIdx.x & 63) == 0) atomicAdd(&e[i >> 9], s);
    }
}

// ---------- K3: Y = x @ P^T (bf16 MFMA); fused gelu(Y+e)*cls_w row-reduce -------
// 256x256 tile, BK=64, 8 waves (wm 0..1 x wn 0..3), 512 thr, 128KB LDS.
// Wave frag mapping: A row(mi)=(mi>>2)*128+wm*64+(mi&3)*16+lo (half qm=mi>>2);
//                    B row(ni)=(ni>>1)*128+wn*32+(ni&1)*16+lo (half qn=ni>>1).
// Per K-tile, 4 quadrant phases in order (0,0),(1,0),(1,1),(0,1) with REG
// REUSE: bfr holds B-half 2 phases, af A-half 2 phases (re-read A0 at p4).
// Reads/phase: 12,8,4,8. Stage ring: 1 half-tile/phase, 3-phase lead,
// vmcnt(6) at phases 4/8 only (= 3 half-tiles x 2 loads in flight).
// NO hand lgkmcnt/sched_barrier: compiler emits per-use lgkmcnt(N) so MFMAs
// overlap this wave's later reads; waves finishing reads early MFMA while
// the LDS pipe serves the rest.
// LDS swizzle: slot(row,c)=c^(row&7) in 16B chunks; staged via pre-swizzled
// GLOBAL src + linear gld16 dst (both-sides rule); reads 2-way on banks (free).
__global__ __launch_bounds__(512, 2) void gemm_kernel(const ushort* __restrict__ X,
                                                      const ushort* __restrict__ P,
                                                      const float* __restrict__ clsW,
                                                      const float* __restrict__ e,
                                                      float* __restrict__ accOut) {
    __shared__ __align__(16) ushort As[2][256 * 64];  // 2 x 32 KB
    __shared__ __align__(16) ushort Bs[2][256 * 64];  // 2 x 32 KB

    const int t = threadIdx.x;
    // bijective XCD swizzle (256 blocks % 8 XCDs == 0)
    const int flat = blockIdx.x;
    const int swz = (flat & 7) * 32 + (flat >> 3);
    const int bRow = swz >> 4, bCol = swz & 15;

    const int lane = t & 63, wv = t >> 6;
    const int g = lane >> 4, lo = lane & 15;
    const int wm = wv >> 2, wn = wv & 3;  // 2 x 4 waves

    f32x4 zero4 = {0.f, 0.f, 0.f, 0.f};
    f32x4 acc[8][4];
#pragma unroll
    for (int mi = 0; mi < 8; ++mi)
#pragma unroll
        for (int ni = 0; ni < 4; ++ni) acc[mi][ni] = zero4;

    bf16x8 af[4][2];   // current A-half fragments (reused across 2 phases)
    bf16x8 bfr[2][2];  // current B-half fragments (reused across 2 phases)
    const int ch0 = ((g ^ (lo & 7)) << 3);        // kk=0 swizzled chunk (ushorts)
    const int ch1 = (((4 | g) ^ (lo & 7)) << 3);  // kk=1

    // staging: per half-tile (128 rows x 64 cols bf16 = 16KB) each thread does
    // 2 gld16: rows sr2, sr2+64; slot t&7 holds global chunk (t&7)^(sr2&7);
    // LDS dst linear = t*16 (+8192).
    const int sr2 = t >> 3;                      // 0..63
    const int cs = (t & 7) ^ (sr2 & 7);          // pre-swizzled global 16B-chunk
    const ushort* gA = X + (size_t)(bRow * 256 + sr2) * K_DIM + cs * 8;
    const ushort* gB = P + (size_t)(bCol * 256 + sr2) * K_DIM + cs * 8;
    char* lA0 = (char*)&As[0][0] + t * 16;
    char* lB0 = (char*)&Bs[0][0] + t * 16;

#define STAGE_A(buf, h, k0)                                                        \
    do {                                                                           \
        gld16(gA + (size_t)((h) * 128) * K_DIM + (k0), lA0 + (buf) * 32768 + (h) * 16384);      \
        gld16(gA + (size_t)((h) * 128 + 64) * K_DIM + (k0), lA0 + (buf) * 32768 + (h) * 16384 + 8192); \
    } while (0)
#define STAGE_B(buf, h, k0)                                                        \
    do {                                                                           \
        gld16(gB + (size_t)((h) * 128) * K_DIM + (k0), lB0 + (buf) * 32768 + (h) * 16384);      \
        gld16(gB + (size_t)((h) * 128 + 64) * K_DIM + (k0), lB0 + (buf) * 32768 + (h) * 16384 + 8192); \
    } while (0)

#define VMW6 asm volatile("s_waitcnt vmcnt(6)" ::: "memory")
#define VMW0 asm volatile("s_waitcnt vmcnt(0)" ::: "memory")
#define NOSTAGE ((void)0)
#define NOWAIT ((void)0)
#define BAR __builtin_amdgcn_s_barrier()

#define READ_A(buf, qm)                                                            \
    _Pragma("unroll") for (int m_ = 0; m_ < 4; ++m_) {                             \
        af[m_][0] = *(const bf16x8*)&As[buf][((qm) * 128 + wm * 64 + m_ * 16 + lo) * 64 + ch0]; \
        af[m_][1] = *(const bf16x8*)&As[buf][((qm) * 128 + wm * 64 + m_ * 16 + lo) * 64 + ch1]; \
    }
#define READ_B(buf, qn)                                                            \
    _Pragma("unroll") for (int n_ = 0; n_ < 2; ++n_) {                             \
        bfr[n_][0] = *(const bf16x8*)&Bs[buf][((qn) * 128 + wn * 32 + n_ * 16 + lo) * 64 + ch0]; \
        bfr[n_][1] = *(const bf16x8*)&Bs[buf][((qn) * 128 + wn * 32 + n_ * 16 + lo) * 64 + ch1]; \
    }
#define MFMA16(qm, qn)                                                             \
    do {                                                                           \
        __builtin_amdgcn_s_setprio(1);                                             \
        _Pragma("unroll") for (int m_ = 0; m_ < 4; ++m_)                           \
            _Pragma("unroll") for (int n_ = 0; n_ < 2; ++n_) {                     \
                acc[(qm) * 4 + m_][(qn) * 2 + n_] = __builtin_amdgcn_mfma_f32_16x16x32_bf16( \
                    af[m_][0], bfr[n_][0], acc[(qm) * 4 + m_][(qn) * 2 + n_], 0, 0, 0); \
                acc[(qm) * 4 + m_][(qn) * 2 + n_] = __builtin_amdgcn_mfma_f32_16x16x32_bf16( \
                    af[m_][1], bfr[n_][1], acc[(qm) * 4 + m_][(qn) * 2 + n_], 0, 0, 0); \
            }                                                                      \
        __builtin_amdgcn_s_setprio(0);                                             \
    } while (0)

// Phases per K-tile on buffer b; reads 12/8/4/8; quadrants (0,0),(1,0),(1,1),(0,1).
// No hand waitcnts: compiler inserts minimal lgkmcnt before each MFMA use.
#define PH1(b, STG) do { READ_A(b, 0); READ_B(b, 0); STG; BAR; MFMA16(0, 0); BAR; } while (0)
#define PH2(b, STG) do { READ_A(b, 1); STG; BAR; MFMA16(1, 0); BAR; } while (0)
#define PH3(b, STG) do { READ_B(b, 1); STG; BAR; MFMA16(1, 1); BAR; } while (0)
#define PH4(b, STG, WAIT) do { READ_A(b, 0); STG; BAR; MFMA16(0, 1); WAIT; BAR; } while (0)

    // Prologue: tile0 all 4 halves + tile1's B0,A1,B1 (A0(T1) staged at p1).
    // vmcnt(6) drains tile0's 8 loads, leaves tile1's 6 in flight.
    STAGE_B(0, 0, 0);  STAGE_A(0, 1, 0);  STAGE_B(0, 1, 0);  STAGE_A(0, 0, 0);
    STAGE_B(1, 0, 64); STAGE_A(1, 1, 64); STAGE_B(1, 1, 64);
    VMW6;
    BAR;

#pragma unroll 1
    for (int k0 = 0; k0 < 3968; k0 += 128) {
        // computes tiles T=k0/64 (db0, p1-4) and T+1 (db1, p5-8).
        // Stage ring (1 half/phase, 3-phase lead; half freed by reuse order):
        PH1(0, STAGE_A(1, 0, k0 + 64));           // A0(T+1)
        PH2(0, STAGE_B(0, 0, k0 + 128));          // B0(T+2) (db0h0B free after p1)
        PH3(0, STAGE_A(0, 1, k0 + 128));          // A1(T+2) (db0h1A free after p2)
        PH4(0, STAGE_B(0, 1, k0 + 128), VMW6);    // B1(T+2); drain T+1 fully
        PH1(1, STAGE_A(0, 0, k0 + 128));          // A0(T+2) (db0h0A free after p4)
        PH2(1, STAGE_B(1, 0, k0 + 192));          // B0(T+3)
        PH3(1, STAGE_A(1, 1, k0 + 192));          // A1(T+3)
        PH4(1, STAGE_B(1, 1, k0 + 192), VMW6);    // B1(T+3); drain T+2 fully
    }
    // Epilogue: tiles 62 (db0) and 63 (db1); only A0(63) left to stage.
    PH1(0, STAGE_A(1, 0, 4032));
    PH2(0, NOSTAGE);
    PH3(0, NOSTAGE);
    PH4(0, NOSTAGE, VMW0);  // tile 63 fully landed
    PH1(1, NOSTAGE);
    PH2(1, NOSTAGE);
    PH3(1, NOSTAGE);
    PH4(1, NOSTAGE, NOWAIT);

#undef PH1
#undef PH2
#undef PH3
#undef PH4
#undef MFMA16
#undef READ_A
#undef READ_B
#undef STAGE_A
#undef STAGE_B

    // Output epilogue: C/D layout col=lane&15, row=(lane>>4)*4+reg (m89-verified).
    // col s(ni) = bCol*256 + (ni>>1)*128 + wn*32 + (ni&1)*16 + lo
    // row y(mi) = bRow*256 + (mi>>2)*128 + wm*64 + (mi&3)*16 + g*4 + r
    float eb[4], cw[4];
#pragma unroll
    for (int ni = 0; ni < 4; ++ni) {
        int s = bCol * 256 + (ni >> 1) * 128 + wn * 32 + (ni & 1) * 16 + lo;
        eb[ni] = e[s];
        cw[ni] = clsW[s];
    }
#pragma unroll
    for (int mi = 0; mi < 8; ++mi) {
        int rowBase = bRow * 256 + (mi >> 2) * 128 + wm * 64 + (mi & 3) * 16 + g * 4;
#pragma unroll
        for (int r = 0; r < 4; ++r) {
            float sum = 0.0f;
#pragma unroll
            for (int ni = 0; ni < 4; ++ni) {
                float y = acc[mi][ni][r] + eb[ni];
                sum += gelu_exact(y) * cw[ni];
            }
            sum += __shfl_xor(sum, 1);
            sum += __shfl_xor(sum, 2);
            sum += __shfl_xor(sum, 4);
            sum += __shfl_xor(sum, 8);
            if (lo == 0) atomicAdd(&accOut[rowBase + r], sum);
        }
    }
}

extern "C" void kernel_launch(void* const* d_in, const int* in_sizes, int n_in,
                              void* d_out, int out_size, void* d_ws, size_t ws_size,
                              hipStream_t stream) {
    const float* x          = (const float*)d_in[0];
    const float* ln1_b      = (const float*)d_in[2];
    const float* cp1_w      = (const float*)d_in[3];
    const float* cp1_b      = (const float*)d_in[4];
    const float* sgu_ln_b   = (const float*)d_in[6];
    const float* sgu_proj_w = (const float*)d_in[7];
    const float* sgu_proj_b = (const float*)d_in[8];
    const float* cp2_w      = (const float*)d_in[9];
    const float* cp2_b      = (const float*)d_in[10];
    const float* pooler_w   = (const float*)d_in[11];
    const float* pooler_b   = (const float*)d_in[12];
    const float* cls_w      = (const float*)d_in[13];
    const float* cls_b      = (const float*)d_in[14];

    // ws layout: xb (32MB bf16) | pb (32MB bf16) | c(16KB) | e(16KB)
    ushort* xb = (ushort*)d_ws;                  // 4096*4096 bf16
    ushort* pb = xb + (size_t)K_DIM * K_DIM;     // 4096*4096 bf16
    float*  fs = (float*)(pb + (size_t)K_DIM * K_DIM);
    float* c_buf = fs;
    float* e_buf = fs + 4096;
    float* out   = (float*)d_out;

    c_kernel<<<16, 256, 0, stream>>>(ln1_b, cp1_w, cp1_b, sgu_ln_b, sgu_proj_w,
                                     sgu_proj_b, cp2_w, cp2_b, cls_b, pooler_b,
                                     c_buf, e_buf, out);
    cvt2_kernel<<<16384, 256, 0, stream>>>(x, xb, pooler_w, pb, c_buf, e_buf);
    gemm_kernel<<<256, 512, 0, stream>>>(xb, pb, cls_w, e_buf, out);
}

// Round 6
// 407.198 us; speedup vs baseline: 1.0029x; 1.0029x over previous
//
#include <hip/hip_runtime.h>

// LatentClassifier collapse (all f32 I/O):
//   All depth-loop layernorms act on singleton axes -> LN(x) == bias exactly.
//   => h = x + c[t];  out = (gelu((x+c) @ P^T + pooler_b)) @ cls_w^T + cls_b
//   c per-column => (x+c)@P^T = x@P^T + d[s], d[s] = sum_t c[t]*P[s,t]
// FP32 inputs, no fp32 MFMA -> convert x,P to bf16 once (ws), one 4096^3 bf16
// MFMA GEMM with fused gelu/cls epilogue atomicAdd into d_out.
//
// R4: 256x128 + per-K syncthreads: 135us, 44%.
// R6: 8-phase, no frag reuse: 177us, 31.5% (LDS-read-bound).
// R7: frag reuse + vmcnt(6) ring + lgkmcnt(0)+sched_barrier(0) x8: 154us, 37%
//     (sched_barrier order-pinning tax, m141).
// R8: all fences removed: 214us, 27% -- raw s_barrier builtin is NOT a memory
//     fence; compiler sank ds_reads below the barrier, serializing each phase.
// R9: template midpoint: BAR; asm lgkmcnt(0) ::: "memory" (anchor reads above
//     it) WITHOUT sched_barrier (MFMAs free to interleave).
//     [R9 bench infra-failed: "container failed twice". R10 = identical rerun.]

#define K_DIM 4096

typedef __bf16 bf16x8 __attribute__((ext_vector_type(8)));
typedef float f32x4 __attribute__((ext_vector_type(4)));

__device__ __forceinline__ ushort f2bf(float f) {
    unsigned int u = __float_as_uint(f);
    u = (u + 0x7fffu + ((u >> 16) & 1u)) >> 16;  // RTNE
    return (ushort)u;
}

__device__ __forceinline__ float gelu_exact(float x) {
    return 0.5f * x * (1.0f + erff(x * 0.70710678118654752440f));
}

__device__ __forceinline__ void gld16(const void* g, void* l) {
    __builtin_amdgcn_global_load_lds(
        (__attribute__((address_space(1))) void*)(g),
        (__attribute__((address_space(3))) void*)(l), 16, 0, 0);
}

// ---------- K1: c[t] (+R rowsum inline, beta==0 fast path); init e, out -------
__global__ __launch_bounds__(256) void c_kernel(const float* __restrict__ ln1_b,
                                                const float* __restrict__ cp1_w,
                                                const float* __restrict__ cp1_b,
                                                const float* __restrict__ sgu_ln_b,
                                                const float* __restrict__ sgu_proj_w,
                                                const float* __restrict__ sgu_proj_b,
                                                const float* __restrict__ cp2_w,
                                                const float* __restrict__ cp2_b,
                                                const float* __restrict__ cls_b,
                                                const float* __restrict__ pooler_b,
                                                float* __restrict__ c,
                                                float* __restrict__ e,
                                                float* __restrict__ out) {
    int t = blockIdx.x * 256 + threadIdx.x;  // 0..4095
    float cv = 0.0f;
#pragma unroll
    for (int i = 0; i < 2; ++i) {
        float alpha = gelu_exact(ln1_b[i] * cp1_w[i * 2 + 0] + cp1_b[i * 2 + 0]);
        float beta  = sgu_ln_b[i];
        float Ri = 0.0f;
        if (beta != 0.0f) {  // never taken with these inputs; kept for correctness
            const float* pr = sgu_proj_w + ((size_t)i * 4096 + t) * K_DIM;
            for (int k = 0; k < K_DIM; k += 4) {
                float4 pv = *(const float4*)&pr[k];
                Ri += pv.x + pv.y + pv.z + pv.w;
            }
        }
        float v = beta * Ri + sgu_proj_b[i * 4096 + t];
        cv += alpha * v * cp2_w[i] + cp2_b[i];
    }
    c[t]   = cv;
    e[t]   = pooler_b[t];  // e accumulated by cvt2_kernel atomics
    out[t] = cls_b[0];     // d_out poisoned before every call -> re-init here
}

// ---------- K2: f32->bf16 convert of x and pooler_w; P-half also accumulates
//               e[row] += sum_col P[row,col]*c[col] (wave-reduced atomic) ------
__global__ __launch_bounds__(256) void cvt2_kernel(const float* __restrict__ s0,
                                                   ushort* __restrict__ d0,
                                                   const float* __restrict__ s1,
                                                   ushort* __restrict__ d1,
                                                   const float* __restrict__ c,
                                                   float* __restrict__ e) {
    int b = blockIdx.x;
    bool isP = (b >= 8192);
    const float* src = isP ? s1 : s0;
    ushort* dst = isP ? d1 : d0;
    int i = (b & 8191) * 256 + threadIdx.x;  // 8 floats each
    const float4* s4 = (const float4*)src + (size_t)i * 2;
    float4 a = s4[0], q = s4[1];
    union { ushort u[8]; uint4 v; } r;
    r.u[0] = f2bf(a.x); r.u[1] = f2bf(a.y); r.u[2] = f2bf(a.z); r.u[3] = f2bf(a.w);
    r.u[4] = f2bf(q.x); r.u[5] = f2bf(q.y); r.u[6] = f2bf(q.z); r.u[7] = f2bf(q.w);
    ((uint4*)dst)[i] = r.v;
    if (isP) {
        // wave's 64 units are 512 consecutive floats inside row i>>9
        int col = (i << 3) & 4095;
        float s = a.x * c[col + 0] + a.y * c[col + 1] + a.z * c[col + 2] + a.w * c[col + 3]
                + q.x * c[col + 4] + q.y * c[col + 5] + q.z * c[col + 6] + q.w * c[col + 7];
#pragma unroll
        for (int m = 1; m < 64; m <<= 1) s += __shfl_xor(s, m);
        if ((threadIdx.x & 63) == 0) atomicAdd(&e[i >> 9], s);
    }
}

// ---------- K3: Y = x @ P^T (bf16 MFMA); fused gelu(Y+e)*cls_w row-reduce -------
// 256x256 tile, BK=64, 8 waves (wm 0..1 x wn 0..3), 512 thr, 128KB LDS.
// Wave frag mapping: A row(mi)=(mi>>2)*128+wm*64+(mi&3)*16+lo (half qm=mi>>2);
//                    B row(ni)=(ni>>1)*128+wn*32+(ni&1)*16+lo (half qn=ni>>1).
// Per K-tile, 4 quadrant phases in order (0,0),(1,0),(1,1),(0,1) with REG
// REUSE: bfr holds B-half 2 phases, af A-half 2 phases (re-read A0 at p4).
// Reads/phase: 12,8,4,8. Stage ring: 1 half-tile/phase, 3-phase lead,
// vmcnt(6) at phases 4/8 only (= 3 half-tiles x 2 loads in flight).
// Phase fence = BAR; asm lgkmcnt(0) w/ "memory" (reads can't sink past it;
// MFMAs may hoist -- compiler still emits its own per-use lgkmcnt). NO
// sched_barrier(0) (R7's pin tax); NOT fenceless (R8's read-sinking).
// LDS swizzle: slot(row,c)=c^(row&7) in 16B chunks; staged via pre-swizzled
// GLOBAL src + linear gld16 dst (both-sides rule); reads 2-way on banks (free).
__global__ __launch_bounds__(512, 2) void gemm_kernel(const ushort* __restrict__ X,
                                                      const ushort* __restrict__ P,
                                                      const float* __restrict__ clsW,
                                                      const float* __restrict__ e,
                                                      float* __restrict__ accOut) {
    __shared__ __align__(16) ushort As[2][256 * 64];  // 2 x 32 KB
    __shared__ __align__(16) ushort Bs[2][256 * 64];  // 2 x 32 KB

    const int t = threadIdx.x;
    // bijective XCD swizzle (256 blocks % 8 XCDs == 0)
    const int flat = blockIdx.x;
    const int swz = (flat & 7) * 32 + (flat >> 3);
    const int bRow = swz >> 4, bCol = swz & 15;

    const int lane = t & 63, wv = t >> 6;
    const int g = lane >> 4, lo = lane & 15;
    const int wm = wv >> 2, wn = wv & 3;  // 2 x 4 waves

    f32x4 zero4 = {0.f, 0.f, 0.f, 0.f};
    f32x4 acc[8][4];
#pragma unroll
    for (int mi = 0; mi < 8; ++mi)
#pragma unroll
        for (int ni = 0; ni < 4; ++ni) acc[mi][ni] = zero4;

    bf16x8 af[4][2];   // current A-half fragments (reused across 2 phases)
    bf16x8 bfr[2][2];  // current B-half fragments (reused across 2 phases)
    const int ch0 = ((g ^ (lo & 7)) << 3);        // kk=0 swizzled chunk (ushorts)
    const int ch1 = (((4 | g) ^ (lo & 7)) << 3);  // kk=1

    // staging: per half-tile (128 rows x 64 cols bf16 = 16KB) each thread does
    // 2 gld16: rows sr2, sr2+64; slot t&7 holds global chunk (t&7)^(sr2&7);
    // LDS dst linear = t*16 (+8192).
    const int sr2 = t >> 3;                      // 0..63
    const int cs = (t & 7) ^ (sr2 & 7);          // pre-swizzled global 16B-chunk
    const ushort* gA = X + (size_t)(bRow * 256 + sr2) * K_DIM + cs * 8;
    const ushort* gB = P + (size_t)(bCol * 256 + sr2) * K_DIM + cs * 8;
    char* lA0 = (char*)&As[0][0] + t * 16;
    char* lB0 = (char*)&Bs[0][0] + t * 16;

#define STAGE_A(buf, h, k0)                                                        \
    do {                                                                           \
        gld16(gA + (size_t)((h) * 128) * K_DIM + (k0), lA0 + (buf) * 32768 + (h) * 16384);      \
        gld16(gA + (size_t)((h) * 128 + 64) * K_DIM + (k0), lA0 + (buf) * 32768 + (h) * 16384 + 8192); \
    } while (0)
#define STAGE_B(buf, h, k0)                                                        \
    do {                                                                           \
        gld16(gB + (size_t)((h) * 128) * K_DIM + (k0), lB0 + (buf) * 32768 + (h) * 16384);      \
        gld16(gB + (size_t)((h) * 128 + 64) * K_DIM + (k0), lB0 + (buf) * 32768 + (h) * 16384 + 8192); \
    } while (0)

#define VMW6 asm volatile("s_waitcnt vmcnt(6)" ::: "memory")
#define VMW0 asm volatile("s_waitcnt vmcnt(0)" ::: "memory")
#define NOSTAGE ((void)0)
#define NOWAIT ((void)0)
#define BAR __builtin_amdgcn_s_barrier()
// Anchor: reads issued before this cannot sink past it ("memory"); no
// sched_barrier -> MFMAs/addr-calc remain schedulable around it.
#define LGKM0 asm volatile("s_waitcnt lgkmcnt(0)" ::: "memory")
#define LGKM8 asm volatile("s_waitcnt lgkmcnt(8)" ::: "memory")

#define READ_A(buf, qm)                                                            \
    _Pragma("unroll") for (int m_ = 0; m_ < 4; ++m_) {                             \
        af[m_][0] = *(const bf16x8*)&As[buf][((qm) * 128 + wm * 64 + m_ * 16 + lo) * 64 + ch0]; \
        af[m_][1] = *(const bf16x8*)&As[buf][((qm) * 128 + wm * 64 + m_ * 16 + lo) * 64 + ch1]; \
    }
#define READ_B(buf, qn)                                                            \
    _Pragma("unroll") for (int n_ = 0; n_ < 2; ++n_) {                             \
        bfr[n_][0] = *(const bf16x8*)&Bs[buf][((qn) * 128 + wn * 32 + n_ * 16 + lo) * 64 + ch0]; \
        bfr[n_][1] = *(const bf16x8*)&Bs[buf][((qn) * 128 + wn * 32 + n_ * 16 + lo) * 64 + ch1]; \
    }
#define MFMA16(qm, qn)                                                             \
    do {                                                                           \
        __builtin_amdgcn_s_setprio(1);                                             \
        _Pragma("unroll") for (int m_ = 0; m_ < 4; ++m_)                           \
            _Pragma("unroll") for (int n_ = 0; n_ < 2; ++n_) {                     \
                acc[(qm) * 4 + m_][(qn) * 2 + n_] = __builtin_amdgcn_mfma_f32_16x16x32_bf16( \
                    af[m_][0], bfr[n_][0], acc[(qm) * 4 + m_][(qn) * 2 + n_], 0, 0, 0); \
                acc[(qm) * 4 + m_][(qn) * 2 + n_] = __builtin_amdgcn_mfma_f32_16x16x32_bf16( \
                    af[m_][1], bfr[n_][1], acc[(qm) * 4 + m_][(qn) * 2 + n_], 0, 0, 0); \
            }                                                                      \
        __builtin_amdgcn_s_setprio(0);                                             \
    } while (0)

// Phases per K-tile on buffer b; reads 12/8/4/8; quadrants (0,0),(1,0),(1,1),(0,1)
#define PH1(b, STG) do { READ_A(b, 0); READ_B(b, 0); STG; LGKM8; BAR; LGKM0; MFMA16(0, 0); BAR; } while (0)
#define PH2(b, STG) do { READ_A(b, 1); STG; BAR; LGKM0; MFMA16(1, 0); BAR; } while (0)
#define PH3(b, STG) do { READ_B(b, 1); STG; BAR; LGKM0; MFMA16(1, 1); BAR; } while (0)
#define PH4(b, STG, WAIT) do { READ_A(b, 0); STG; BAR; LGKM0; MFMA16(0, 1); WAIT; BAR; } while (0)

    // Prologue: tile0 all 4 halves + tile1's B0,A1,B1 (A0(T1) staged at p1).
    // vmcnt(6) drains tile0's 8 loads, leaves tile1's 6 in flight.
    STAGE_B(0, 0, 0);  STAGE_A(0, 1, 0);  STAGE_B(0, 1, 0);  STAGE_A(0, 0, 0);
    STAGE_B(1, 0, 64); STAGE_A(1, 1, 64); STAGE_B(1, 1, 64);
    VMW6;
    BAR;

#pragma unroll 1
    for (int k0 = 0; k0 < 3968; k0 += 128) {
        // computes tiles T=k0/64 (db0, p1-4) and T+1 (db1, p5-8).
        // Stage ring (1 half/phase, 3-phase lead; half freed by reuse order):
        PH1(0, STAGE_A(1, 0, k0 + 64));           // A0(T+1)
        PH2(0, STAGE_B(0, 0, k0 + 128));          // B0(T+2) (db0h0B free after p1)
        PH3(0, STAGE_A(0, 1, k0 + 128));          // A1(T+2) (db0h1A free after p2)
        PH4(0, STAGE_B(0, 1, k0 + 128), VMW6);    // B1(T+2); drain T+1 fully
        PH1(1, STAGE_A(0, 0, k0 + 128));          // A0(T+2) (db0h0A free after p4)
        PH2(1, STAGE_B(1, 0, k0 + 192));          // B0(T+3)
        PH3(1, STAGE_A(1, 1, k0 + 192));          // A1(T+3)
        PH4(1, STAGE_B(1, 1, k0 + 192), VMW6);    // B1(T+3); drain T+2 fully
    }
    // Epilogue: tiles 62 (db0) and 63 (db1); only A0(63) left to stage.
    PH1(0, STAGE_A(1, 0, 4032));
    PH2(0, NOSTAGE);
    PH3(0, NOSTAGE);
    PH4(0, NOSTAGE, VMW0);  // tile 63 fully landed
    PH1(1, NOSTAGE);
    PH2(1, NOSTAGE);
    PH3(1, NOSTAGE);
    PH4(1, NOSTAGE, NOWAIT);

#undef PH1
#undef PH2
#undef PH3
#undef PH4
#undef MFMA16
#undef READ_A
#undef READ_B
#undef STAGE_A
#undef STAGE_B

    // Output epilogue: C/D layout col=lane&15, row=(lane>>4)*4+reg (m89-verified).
    // col s(ni) = bCol*256 + (ni>>1)*128 + wn*32 + (ni&1)*16 + lo
    // row y(mi) = bRow*256 + (mi>>2)*128 + wm*64 + (mi&3)*16 + g*4 + r
    float eb[4], cw[4];
#pragma unroll
    for (int ni = 0; ni < 4; ++ni) {
        int s = bCol * 256 + (ni >> 1) * 128 + wn * 32 + (ni & 1) * 16 + lo;
        eb[ni] = e[s];
        cw[ni] = clsW[s];
    }
#pragma unroll
    for (int mi = 0; mi < 8; ++mi) {
        int rowBase = bRow * 256 + (mi >> 2) * 128 + wm * 64 + (mi & 3) * 16 + g * 4;
#pragma unroll
        for (int r = 0; r < 4; ++r) {
            float sum = 0.0f;
#pragma unroll
            for (int ni = 0; ni < 4; ++ni) {
                float y = acc[mi][ni][r] + eb[ni];
                sum += gelu_exact(y) * cw[ni];
            }
            sum += __shfl_xor(sum, 1);
            sum += __shfl_xor(sum, 2);
            sum += __shfl_xor(sum, 4);
            sum += __shfl_xor(sum, 8);
            if (lo == 0) atomicAdd(&accOut[rowBase + r], sum);
        }
    }
}

extern "C" void kernel_launch(void* const* d_in, const int* in_sizes, int n_in,
                              void* d_out, int out_size, void* d_ws, size_t ws_size,
                              hipStream_t stream) {
    const float* x          = (const float*)d_in[0];
    const float* ln1_b      = (const float*)d_in[2];
    const float* cp1_w      = (const float*)d_in[3];
    const float* cp1_b      = (const float*)d_in[4];
    const float* sgu_ln_b   = (const float*)d_in[6];
    const float* sgu_proj_w = (const float*)d_in[7];
    const float* sgu_proj_b = (const float*)d_in[8];
    const float* cp2_w      = (const float*)d_in[9];
    const float* cp2_b      = (const float*)d_in[10];
    const float* pooler_w   = (const float*)d_in[11];
    const float* pooler_b   = (const float*)d_in[12];
    const float* cls_w      = (const float*)d_in[13];
    const float* cls_b      = (const float*)d_in[14];

    // ws layout: xb (32MB bf16) | pb (32MB bf16) | c(16KB) | e(16KB)
    ushort* xb = (ushort*)d_ws;                  // 4096*4096 bf16
    ushort* pb = xb + (size_t)K_DIM * K_DIM;     // 4096*4096 bf16
    float*  fs = (float*)(pb + (size_t)K_DIM * K_DIM);
    float* c_buf = fs;
    float* e_buf = fs + 4096;
    float* out   = (float*)d_out;

    c_kernel<<<16, 256, 0, stream>>>(ln1_b, cp1_w, cp1_b, sgu_ln_b, sgu_proj_w,
                                     sgu_proj_b, cp2_w, cp2_b, cls_b, pooler_b,
                                     c_buf, e_buf, out);
    cvt2_kernel<<<16384, 256, 0, stream>>>(x, xb, pooler_w, pb, c_buf, e_buf);
    gemm_kernel<<<256, 512, 0, stream>>>(xb, pb, cls_w, e_buf, out);
}